// Round 2
// baseline (1973.419 us; speedup 1.0000x reference)
//
#include <hip/hip_runtime.h>

typedef _Float16 half8 __attribute__((ext_vector_type(8)));
typedef float floatx16 __attribute__((ext_vector_type(16)));

constexpr int Gn = 5;
constexpr int Bn = 131072;
constexpr int Kn = 512;
constexpr int Dn = 64;

constexpr long long QOFF = (long long)Gn * Bn * Dn;  // end of quantized block
constexpr long long IOFF = QOFF + Gn + 1;            // start of indices block
constexpr unsigned CAPE = 131072;                    // rescue-entry capacity

// ---------------------------------------------------------------------------
// esq[g*K+k] = sum_d code[g,k,d]^2 — same kernel as round 1 (values feed the
// EXACT distance formula in vq_rescue; must stay bit-identical to R1)
// ---------------------------------------------------------------------------
__global__ void vq_esq(const float* __restrict__ code, float* __restrict__ esq) {
    int i = blockIdx.x * blockDim.x + threadIdx.x;
    if (i >= Gn * Kn) return;
    const float4* c4 = reinterpret_cast<const float4*>(code + (long long)i * Dn);
    float s0 = 0.f, s1 = 0.f, s2 = 0.f, s3 = 0.f;
#pragma unroll
    for (int j = 0; j < 16; ++j) {
        float4 v = c4[j];
        s0 += v.x * v.x; s1 += v.y * v.y; s2 += v.z * v.z; s3 += v.w * v.w;
    }
    esq[i] = (s0 + s1) + (s2 + s3);
}

// ---------------------------------------------------------------------------
// codebook fp32 -> fp16 copy (for MFMA screening) + cbias = 1 + esq/2
// ---------------------------------------------------------------------------
__global__ void vq_cvt(const float* __restrict__ code, const float* __restrict__ esq,
                       _Float16* __restrict__ code16, float* __restrict__ cbias) {
    int i = blockIdx.x * blockDim.x + threadIdx.x;
    if (i < Gn * Kn * Dn) code16[i] = (_Float16)code[i];
    if (i < Gn * Kn) cbias[i] = 1.0f + 0.5f * esq[i];
}

// ---------------------------------------------------------------------------
// MFMA screening kernel. Per wave: 64 batch rows (2 MFMA row-tiles), sweep
// 16 col-chunks of 32 codes. mdist = (1 + esq/2) - dot, fp16 inputs, fp32 acc.
// Top-2 (v1,v2) per row tracked with chunk-id packed into v1/v2 low 4 bits.
// Rows with v2-v1 <= analytic fp16 error margin are appended for exact rescue.
// No LDS, no barriers: A fragments live in registers, B streams from L1/L2.
// ---------------------------------------------------------------------------
__global__ __launch_bounds__(256, 2) void vq_screen(
    const float* __restrict__ feat, const float* __restrict__ codef,
    const _Float16* __restrict__ code16, const float* __restrict__ cbias,
    float* __restrict__ out, float* __restrict__ acc,
    unsigned* __restrict__ cnt, unsigned* __restrict__ entries)
{
    const int g = blockIdx.y;
    const int lane = threadIdx.x & 63;
    const int wv = threadIdx.x >> 6;
    const int l31 = lane & 31;
    const int hh = lane >> 5;
    const long long rowbase = (long long)blockIdx.x * 256 + wv * 64;

    // ---- A staging: fp32 global -> fp16 fragments in registers ------------
    // 32x32x16 A layout: m = lane&31, k = 8*(lane>>5) + j (+16 per k-step)
    half8 aF[2][4];
    float xsq_p[2], sax_p[2];   // per-lane: row (lane&31) of tile t
    const float* fg = feat + ((long long)g * Bn + rowbase) * Dn;
#pragma unroll
    for (int t = 0; t < 2; ++t) {
        const float* rp = fg + (long long)(t * 32 + l31) * Dn + hh * 8;
        float xs = 0.f, sa = 0.f;
#pragma unroll
        for (int s = 0; s < 4; ++s) {
            float4 u0 = *(const float4*)(rp + 16 * s);
            float4 u1 = *(const float4*)(rp + 16 * s + 4);
            half8 a;
            a[0] = (_Float16)u0.x; a[1] = (_Float16)u0.y;
            a[2] = (_Float16)u0.z; a[3] = (_Float16)u0.w;
            a[4] = (_Float16)u1.x; a[5] = (_Float16)u1.y;
            a[6] = (_Float16)u1.z; a[7] = (_Float16)u1.w;
            aF[t][s] = a;
            xs += u0.x*u0.x + u0.y*u0.y + u0.z*u0.z + u0.w*u0.w
                + u1.x*u1.x + u1.y*u1.y + u1.z*u1.z + u1.w*u1.w;
            sa += fabsf(u0.x) + fabsf(u0.y) + fabsf(u0.z) + fabsf(u0.w)
                + fabsf(u1.x) + fabsf(u1.y) + fabsf(u1.z) + fabsf(u1.w);
        }
        xs += __shfl_xor(xs, 32);   // other half-lane holds the other 32 dims
        sa += __shfl_xor(sa, 32);
        xsq_p[t] = xs; sax_p[t] = sa;
    }

    // ---- main loop over 16 col-chunks -------------------------------------
    float v1[2][16], v2[2][16];
#pragma unroll
    for (int t = 0; t < 2; ++t)
#pragma unroll
        for (int r = 0; r < 16; ++r) { v1[t][r] = 3.0e38f; v2[t][r] = 3.0e38f; }

    const _Float16* bbase = code16 + ((long long)g * Kn + l31) * Dn + hh * 8;
    for (int ch = 0; ch < 16; ++ch) {
        float c = cbias[g * Kn + ch * 32 + l31];    // col = ch*32 + l31
        const _Float16* bp = bbase + (long long)ch * 32 * Dn;
        half8 bF[4];
#pragma unroll
        for (int s = 0; s < 4; ++s) bF[s] = *(const half8*)(bp + 16 * s);

        floatx16 acc0 = {0.f}, acc1 = {0.f};
#pragma unroll
        for (int s = 0; s < 4; ++s) {
            acc0 = __builtin_amdgcn_mfma_f32_32x32x16_f16(aF[0][s], bF[s], acc0, 0, 0, 0);
            acc1 = __builtin_amdgcn_mfma_f32_32x32x16_f16(aF[1][s], bF[s], acc1, 0, 0, 0);
        }
#pragma unroll
        for (int r = 0; r < 16; ++r) {
            float cd0 = c - acc0[r];   // mdist in (0.8, 1.2)
            cd0 = __int_as_float((__float_as_int(cd0) & ~15) | ch);
            v2[0][r] = fminf(v2[0][r], fmaxf(v1[0][r], cd0));
            v1[0][r] = fminf(v1[0][r], cd0);
            float cd1 = c - acc1[r];
            cd1 = __int_as_float((__float_as_int(cd1) & ~15) | ch);
            v2[1][r] = fminf(v2[1][r], fmaxf(v1[1][r], cd1));
            v1[1][r] = fminf(v1[1][r], cd1);
        }
    }

    // ---- col recovery + cross-lane top-2 butterfly (within 32-lane half) --
    int col[2][16];
#pragma unroll
    for (int t = 0; t < 2; ++t)
#pragma unroll
        for (int r = 0; r < 16; ++r)
            col[t][r] = ((__float_as_int(v1[t][r]) & 15) << 5) + l31;

#pragma unroll
    for (int mi = 0; mi < 5; ++mi) {
        const int m = 1 << mi;
#pragma unroll
        for (int t = 0; t < 2; ++t)
#pragma unroll
            for (int r = 0; r < 16; ++r) {
                float ov1 = __shfl_xor(v1[t][r], m);
                float ov2 = __shfl_xor(v2[t][r], m);
                int   oc  = __shfl_xor(col[t][r], m);
                float mx = fmaxf(v1[t][r], ov1);
                v2[t][r] = fminf(fminf(v2[t][r], ov2), mx);
                if (ov1 < v1[t][r]) { v1[t][r] = ov1; col[t][r] = oc; }
                // exact packed tie across lanes -> v2==v1 -> gap 0 -> flagged
            }
    }

    // ---- epilogue: gather quantized, indices, margin flag, loss -----------
    float lsum = 0.f;
#pragma unroll
    for (int t = 0; t < 2; ++t) {
#pragma unroll
        for (int r = 0; r < 16; ++r) {
            const int ra = (r & 3) + 8 * (r >> 2) + 4 * hh;  // C/D row map
            const long long grow = rowbase + t * 32 + ra;
            const int cc = col[t][r];
            // cooperative row gather: 32 lanes x float2 = 64 floats
            const float* qsrc = codef + ((long long)(g * Kn + cc)) * Dn;
            float2 qv = *(const float2*)(qsrc + 2 * l31);
            *(float2*)(out + ((long long)g * Bn + grow) * Dn + 2 * l31) = qv;
            if (l31 == ra) {   // writer lane also holds row ra's xsq/sax
                out[IOFF + (long long)g * Bn + grow] = (float)cc;
                float v1c = __int_as_float(__float_as_int(v1[t][r]) & ~15);
                float v2c = __int_as_float(__float_as_int(v2[t][r]) & ~15);
                // dist = xsq + 2*(mdist - 1); loss tolerance is huge
                lsum += xsq_p[t] + 2.0f * (v1c - 1.0f);
                // analytic fp16 screening error: dot err <= sax*(1/512)*2^-10
                float margin = sax_p[t] * 4.0e-6f + 1.2e-5f;
                if (v2c - v1c <= margin) {
                    unsigned slot = atomicAdd(cnt, 1u);
                    if (slot < CAPE)
                        entries[slot] = ((unsigned)g << 17) | (unsigned)grow;
                }
            }
        }
    }
#pragma unroll
    for (int m = 1; m < 64; m <<= 1) lsum += __shfl_xor(lsum, m);
    if (lane == 0) atomicAdd(&acc[g], lsum);
}

// ---------------------------------------------------------------------------
// Exact rescue: one wave per flagged row, full K=512 scan with the SAME exact
// fp32 formula as round 1 (pairwise-8 xsq, 4-acc fmaf dot, strict-< ascending
// k). Overwrites index + quantized row.
// ---------------------------------------------------------------------------
__global__ __launch_bounds__(256) void vq_rescue(
    const float* __restrict__ feat, const float* __restrict__ codef,
    const float* __restrict__ esq, const unsigned* __restrict__ cnt,
    const unsigned* __restrict__ entries, float* __restrict__ out)
{
    const int lane = threadIdx.x & 63;
    const int wid = blockIdx.x * 4 + (threadIdx.x >> 6);
    const int nw = gridDim.x * 4;
    const int n = (int)min(*cnt, CAPE);

    for (int i = wid; i < n; i += nw) {
        unsigned e = entries[i];
        int g = e >> 17;
        long long b = e & 131071u;

        const float* xp = feat + ((long long)g * Bn + b) * Dn;
        float x[64];
#pragma unroll
        for (int j = 0; j < 16; ++j) {
            float4 u = ((const float4*)xp)[j];
            x[4*j] = u.x; x[4*j+1] = u.y; x[4*j+2] = u.z; x[4*j+3] = u.w;
        }
        float xsq;
        {
#pragma clang fp contract(off)
            float r0[8];
#pragma unroll
            for (int j = 0; j < 8; ++j) r0[j] = x[j] * x[j];
#pragma unroll
            for (int q = 8; q < 64; q += 8)
#pragma unroll
                for (int j = 0; j < 8; ++j) {
                    float s0 = x[q + j] * x[q + j];
                    r0[j] = r0[j] + s0;
                }
            xsq = ((r0[0] + r0[1]) + (r0[2] + r0[3])) + ((r0[4] + r0[5]) + (r0[6] + r0[7]));
        }

        const float* cg = codef + (long long)g * Kn * Dn;
        const float* eg = esq + g * Kn;
        float best = 3.4e38f; int bk = 0x7fffffff;
        for (int j = 0; j < 8; ++j) {
            int k = j * 64 + lane;
            const float4* cp = (const float4*)(cg + (long long)k * Dn);
            float d0 = 0.f, d1 = 0.f, d2 = 0.f, d3 = 0.f;
#pragma unroll
            for (int q = 0; q < 16; ++q) {
                float4 v = cp[q];
                d0 = fmaf(v.x, x[4*q+0], d0);
                d1 = fmaf(v.y, x[4*q+1], d1);
                d2 = fmaf(v.z, x[4*q+2], d2);
                d3 = fmaf(v.w, x[4*q+3], d3);
            }
            float dot = (d0 + d1) + (d2 + d3);
            float dist = (xsq + eg[k]) - 2.0f * dot;
            if (dist < best) { best = dist; bk = k; }
        }
#pragma unroll
        for (int m = 1; m < 64; m <<= 1) {
            float ov = __shfl_xor(best, m);
            int   ok = __shfl_xor(bk, m);
            if (ov < best || (ov == best && ok < bk)) { best = ov; bk = ok; }
        }
        if (lane == 0) out[IOFF + (long long)g * Bn + b] = (float)bk;
        out[((long long)g * Bn + b) * Dn + lane] = cg[(long long)bk * Dn + lane];
    }
}

// ---------------------------------------------------------------------------
// per_group_loss = 1.25 * SSE / 2^23; total = sequential sum over 5 groups
// ---------------------------------------------------------------------------
__global__ void vq_finalize(const float* __restrict__ acc, float* __restrict__ out) {
    if (threadIdx.x == 0 && blockIdx.x == 0) {
        float tot = 0.f;
#pragma unroll
        for (int g = 0; g < Gn; ++g) {
            float m = acc[g] / 8388608.0f;
            float l = m + 0.25f * m;
            out[QOFF + g] = l;
            tot += l;
        }
        out[QOFF + Gn] = tot;
    }
}

extern "C" void kernel_launch(void* const* d_in, const int* in_sizes, int n_in,
                              void* d_out, int out_size, void* d_ws, size_t ws_size,
                              hipStream_t stream) {
    const float* feat = (const float*)d_in[0];   // [G,B,D] fp32
    const float* code = (const float*)d_in[1];   // [G,K,D] fp32
    float* out = (float*)d_out;

    char* w = (char*)d_ws;
    float*     acc     = (float*)w;                    // [0,64)    loss acc
    unsigned*  cnt     = (unsigned*)(w + 64);          // [64,128)  rescue count
    float*     esq     = (float*)(w + 128);            // 5*512*4   = 10240
    float*     cbias   = (float*)(w + 128 + 10240);    // 5*512*4   = 10240
    _Float16*  code16  = (_Float16*)(w + 20608);       // 5*512*64*2 = 327680
    unsigned*  entries = (unsigned*)(w + 348288);      // 131072*4  = 524288

    hipMemsetAsync(w, 0, 128, stream);
    vq_esq<<<(Gn * Kn + 255) / 256, 256, 0, stream>>>(code, esq);
    vq_cvt<<<(Gn * Kn * Dn + 255) / 256, 256, 0, stream>>>(code, esq, code16, cbias);
    dim3 grid(Bn / 256, Gn);
    vq_screen<<<grid, 256, 0, stream>>>(feat, code, code16, cbias, out, acc, cnt, entries);
    vq_rescue<<<320, 256, 0, stream>>>(feat, code, esq, cnt, entries, out);
    vq_finalize<<<1, 64, 0, stream>>>(acc, out);
}

// Round 3
// 654.890 us; speedup vs baseline: 3.0134x; 3.0134x over previous
//
#include <hip/hip_runtime.h>

typedef _Float16 half8 __attribute__((ext_vector_type(8)));
typedef float floatx16 __attribute__((ext_vector_type(16)));

constexpr int Gn = 5;
constexpr int Bn = 131072;
constexpr int Kn = 512;
constexpr int Dn = 64;

constexpr long long QOFF = (long long)Gn * Bn * Dn;  // end of quantized block
constexpr long long IOFF = QOFF + Gn + 1;            // start of indices block
constexpr unsigned CAPE = 49152;                     // rescue-entry capacity

// ---------------------------------------------------------------------------
// esq[g*K+k] = sum_d code[g,k,d]^2 — feeds vq_rescue's EXACT distance formula
// (bit-identical to round 1's kernel; do not change accumulation order)
// ---------------------------------------------------------------------------
__global__ void vq_esq(const float* __restrict__ code, float* __restrict__ esq) {
    int i = blockIdx.x * blockDim.x + threadIdx.x;
    if (i >= Gn * Kn) return;
    const float4* c4 = reinterpret_cast<const float4*>(code + (long long)i * Dn);
    float s0 = 0.f, s1 = 0.f, s2 = 0.f, s3 = 0.f;
#pragma unroll
    for (int j = 0; j < 16; ++j) {
        float4 v = c4[j];
        s0 += v.x * v.x; s1 += v.y * v.y; s2 += v.z * v.z; s3 += v.w * v.w;
    }
    esq[i] = (s0 + s1) + (s2 + s3);
}

// ---------------------------------------------------------------------------
// Split-fp16 codebook: eh = fp16(e), el_s = fp16((e-eh)*2048)  (scaled so the
// lo part never hits fp16-denormal range inside the MFMA), cbias = 1 + esq/2
// ---------------------------------------------------------------------------
__global__ void vq_cvt(const float* __restrict__ code, const float* __restrict__ esq,
                       _Float16* __restrict__ ch16, _Float16* __restrict__ cl16,
                       float* __restrict__ cbias) {
    int i = blockIdx.x * blockDim.x + threadIdx.x;
    if (i < Gn * Kn * Dn) {
        float v = code[i];
        _Float16 h = (_Float16)v;
        ch16[i] = h;
        cl16[i] = (_Float16)((v - (float)h) * 2048.0f);
    }
    if (i < Gn * Kn) cbias[i] = 1.0f + 0.5f * esq[i];
}

// ---------------------------------------------------------------------------
// Split-fp16 MFMA screening: dot = ah.bh + 2^-11*(al_s.bh + ah.bl_s).
// accH = ah.bh (unit scale); accL = al_s.bh + ah.bl_s (2048x scale).
// mdist = cbias - dot; top-2 per row, 4-bit chunk id packed in mantissa LSBs.
// Rows with gap <= MARGIN flagged via ballot+popcount: <=1 atomicAdd per wave.
// ---------------------------------------------------------------------------
__global__ __launch_bounds__(256, 2) void vq_screen(
    const float* __restrict__ feat, const float* __restrict__ codef,
    const _Float16* __restrict__ ch16, const _Float16* __restrict__ cl16,
    const float* __restrict__ cbias, float* __restrict__ out,
    float* __restrict__ acc, unsigned* __restrict__ cnt,
    unsigned* __restrict__ entries)
{
    const int g = blockIdx.y;
    const int lane = threadIdx.x & 63;
    const int wv = threadIdx.x >> 6;
    const int l31 = lane & 31;
    const int hh = lane >> 5;
    const long long rowbase = (long long)blockIdx.x * 256 + wv * 64;
    const float MARGIN = 4.0e-5f;     // mdist units; see error budget in notes

    // ---- A staging: fp32 -> (hi, lo*2048) fp16 fragments ------------------
    // 32x32x16 A layout: m = lane&31, k = 8*(lane>>5) + j + 16*s
    half8 aH[2][4], aL[2][4];
    float xsq_p[2];
    const float* fg = feat + ((long long)g * Bn + rowbase) * Dn;
#pragma unroll
    for (int t = 0; t < 2; ++t) {
        const float* rp = fg + (long long)(t * 32 + l31) * Dn + hh * 8;
        float xs = 0.f;
#pragma unroll
        for (int s = 0; s < 4; ++s) {
            float4 u0 = *(const float4*)(rp + 16 * s);
            float4 u1 = *(const float4*)(rp + 16 * s + 4);
            half8 h, l;
            h[0] = (_Float16)u0.x; h[1] = (_Float16)u0.y;
            h[2] = (_Float16)u0.z; h[3] = (_Float16)u0.w;
            h[4] = (_Float16)u1.x; h[5] = (_Float16)u1.y;
            h[6] = (_Float16)u1.z; h[7] = (_Float16)u1.w;
            l[0] = (_Float16)((u0.x - (float)h[0]) * 2048.0f);
            l[1] = (_Float16)((u0.y - (float)h[1]) * 2048.0f);
            l[2] = (_Float16)((u0.z - (float)h[2]) * 2048.0f);
            l[3] = (_Float16)((u0.w - (float)h[3]) * 2048.0f);
            l[4] = (_Float16)((u1.x - (float)h[4]) * 2048.0f);
            l[5] = (_Float16)((u1.y - (float)h[5]) * 2048.0f);
            l[6] = (_Float16)((u1.z - (float)h[6]) * 2048.0f);
            l[7] = (_Float16)((u1.w - (float)h[7]) * 2048.0f);
            aH[t][s] = h; aL[t][s] = l;
            xs += u0.x*u0.x + u0.y*u0.y + u0.z*u0.z + u0.w*u0.w
                + u1.x*u1.x + u1.y*u1.y + u1.z*u1.z + u1.w*u1.w;
        }
        xs += __shfl_xor(xs, 32);
        xsq_p[t] = xs;
    }

    // ---- 16 col-chunks of 32 codes, B prefetched one chunk ahead ----------
    float v1[2][16], v2[2][16];
#pragma unroll
    for (int t = 0; t < 2; ++t)
#pragma unroll
        for (int r = 0; r < 16; ++r) { v1[t][r] = 3.0e38f; v2[t][r] = 3.0e38f; }

    const _Float16* bbh = ch16 + ((long long)g * Kn + l31) * Dn + hh * 8;
    const _Float16* bbl = cl16 + ((long long)g * Kn + l31) * Dn + hh * 8;
    half8 bH[4], bL[4];
#pragma unroll
    for (int s = 0; s < 4; ++s) {
        bH[s] = *(const half8*)(bbh + 16 * s);
        bL[s] = *(const half8*)(bbl + 16 * s);
    }

    for (int ch = 0; ch < 16; ++ch) {
        float c = cbias[g * Kn + ch * 32 + l31];
        half8 nH[4], nL[4];
        if (ch < 15) {
            const _Float16* ph = bbh + (long long)(ch + 1) * 32 * Dn;
            const _Float16* pl = bbl + (long long)(ch + 1) * 32 * Dn;
#pragma unroll
            for (int s = 0; s < 4; ++s) {
                nH[s] = *(const half8*)(ph + 16 * s);
                nL[s] = *(const half8*)(pl + 16 * s);
            }
        }
        floatx16 h0 = {0.f}, h1 = {0.f}, lo0 = {0.f}, lo1 = {0.f};
#pragma unroll
        for (int s = 0; s < 4; ++s) {
            h0  = __builtin_amdgcn_mfma_f32_32x32x16_f16(aH[0][s], bH[s], h0, 0, 0, 0);
            h1  = __builtin_amdgcn_mfma_f32_32x32x16_f16(aH[1][s], bH[s], h1, 0, 0, 0);
            lo0 = __builtin_amdgcn_mfma_f32_32x32x16_f16(aL[0][s], bH[s], lo0, 0, 0, 0);
            lo1 = __builtin_amdgcn_mfma_f32_32x32x16_f16(aL[1][s], bH[s], lo1, 0, 0, 0);
        }
#pragma unroll
        for (int s = 0; s < 4; ++s) {
            lo0 = __builtin_amdgcn_mfma_f32_32x32x16_f16(aH[0][s], bL[s], lo0, 0, 0, 0);
            lo1 = __builtin_amdgcn_mfma_f32_32x32x16_f16(aH[1][s], bL[s], lo1, 0, 0, 0);
        }
#pragma unroll
        for (int r = 0; r < 16; ++r) {
            float cd0 = (c - h0[r]) - 4.8828125e-4f * lo0[r];   // 2^-11
            cd0 = __int_as_float((__float_as_int(cd0) & ~15) | ch);
            v2[0][r] = fminf(v2[0][r], fmaxf(v1[0][r], cd0));
            v1[0][r] = fminf(v1[0][r], cd0);
            float cd1 = (c - h1[r]) - 4.8828125e-4f * lo1[r];
            cd1 = __int_as_float((__float_as_int(cd1) & ~15) | ch);
            v2[1][r] = fminf(v2[1][r], fmaxf(v1[1][r], cd1));
            v1[1][r] = fminf(v1[1][r], cd1);
        }
        if (ch < 15) {
#pragma unroll
            for (int s = 0; s < 4; ++s) { bH[s] = nH[s]; bL[s] = nL[s]; }
        }
    }

    // ---- col recovery + cross-lane top-2 butterfly (32-lane halves) -------
    int col[2][16];
#pragma unroll
    for (int t = 0; t < 2; ++t)
#pragma unroll
        for (int r = 0; r < 16; ++r)
            col[t][r] = ((__float_as_int(v1[t][r]) & 15) << 5) + l31;

#pragma unroll
    for (int mi = 0; mi < 5; ++mi) {
        const int m = 1 << mi;
#pragma unroll
        for (int t = 0; t < 2; ++t)
#pragma unroll
            for (int r = 0; r < 16; ++r) {
                float ov1 = __shfl_xor(v1[t][r], m);
                float ov2 = __shfl_xor(v2[t][r], m);
                int   oc  = __shfl_xor(col[t][r], m);
                float mx = fmaxf(v1[t][r], ov1);
                v2[t][r] = fminf(fminf(v2[t][r], ov2), mx);
                if (ov1 < v1[t][r]) { v1[t][r] = ov1; col[t][r] = oc; }
            }
    }

    // ---- epilogue: gather quantized, indices, flags, loss -----------------
    float lsum = 0.f;
    bool fl[2] = {false, false};
    unsigned rw[2] = {0u, 0u};
#pragma unroll
    for (int t = 0; t < 2; ++t) {
#pragma unroll
        for (int r = 0; r < 16; ++r) {
            const int ra = (r & 3) + 8 * (r >> 2) + 4 * hh;  // C/D row map
            const long long grow = rowbase + t * 32 + ra;
            const int cc = col[t][r];
            const float* qsrc = codef + ((long long)(g * Kn + cc)) * Dn;
            float2 qv = *(const float2*)(qsrc + 2 * l31);
            *(float2*)(out + ((long long)g * Bn + grow) * Dn + 2 * l31) = qv;
            if (l31 == ra) {
                out[IOFF + (long long)g * Bn + grow] = (float)cc;
                float v1c = __int_as_float(__float_as_int(v1[t][r]) & ~15);
                float v2c = __int_as_float(__float_as_int(v2[t][r]) & ~15);
                lsum += xsq_p[t] + 2.0f * (v1c - 1.0f);
                fl[t] = (v2c - v1c <= MARGIN);
                rw[t] = (unsigned)grow;
            }
        }
    }

    // ---- wave-aggregated rescue-entry append (<=1 atomic per wave) --------
    unsigned long long m0 = __ballot(fl[0]);
    unsigned long long m1 = __ballot(fl[1]);
    unsigned tot = (unsigned)(__builtin_popcountll(m0) + __builtin_popcountll(m1));
    if (tot) {
        unsigned base = 0;
        if (lane == 0) base = atomicAdd(cnt, tot);
        base = (unsigned)__shfl((int)base, 0);
        unsigned long long lt = ((unsigned long long)1 << lane) - 1;
        if (fl[0]) {
            unsigned s = base + (unsigned)__builtin_popcountll(m0 & lt);
            if (s < CAPE) entries[s] = ((unsigned)g << 17) | rw[0];
        }
        if (fl[1]) {
            unsigned s = base + (unsigned)__builtin_popcountll(m0)
                              + (unsigned)__builtin_popcountll(m1 & lt);
            if (s < CAPE) entries[s] = ((unsigned)g << 17) | rw[1];
        }
    }
#pragma unroll
    for (int m = 1; m < 64; m <<= 1) lsum += __shfl_xor(lsum, m);
    if (lane == 0) atomicAdd(&acc[g], lsum);
}

// ---------------------------------------------------------------------------
// Exact rescue: one wave per flagged row, full K=512 scan with round-1's
// bit-exact fp32 formula (pairwise-8 xsq, 4-acc fmaf dot, first-index ties).
// ---------------------------------------------------------------------------
__global__ __launch_bounds__(256) void vq_rescue(
    const float* __restrict__ feat, const float* __restrict__ codef,
    const float* __restrict__ esq, const unsigned* __restrict__ cnt,
    const unsigned* __restrict__ entries, float* __restrict__ out)
{
    const int lane = threadIdx.x & 63;
    const int wid = blockIdx.x * 4 + (threadIdx.x >> 6);
    const int nw = gridDim.x * 4;
    const int n = (int)min(*cnt, CAPE);

    for (int i = wid; i < n; i += nw) {
        unsigned e = entries[i];
        int g = e >> 17;
        long long b = e & 131071u;

        const float* xp = feat + ((long long)g * Bn + b) * Dn;
        float x[64];
#pragma unroll
        for (int j = 0; j < 16; ++j) {
            float4 u = ((const float4*)xp)[j];
            x[4*j] = u.x; x[4*j+1] = u.y; x[4*j+2] = u.z; x[4*j+3] = u.w;
        }
        float xsq;
        {
#pragma clang fp contract(off)
            float r0[8];
#pragma unroll
            for (int j = 0; j < 8; ++j) r0[j] = x[j] * x[j];
#pragma unroll
            for (int q = 8; q < 64; q += 8)
#pragma unroll
                for (int j = 0; j < 8; ++j) {
                    float s0 = x[q + j] * x[q + j];
                    r0[j] = r0[j] + s0;
                }
            xsq = ((r0[0] + r0[1]) + (r0[2] + r0[3])) + ((r0[4] + r0[5]) + (r0[6] + r0[7]));
        }

        const float* cg = codef + (long long)g * Kn * Dn;
        const float* eg = esq + g * Kn;
        float best = 3.4e38f; int bk = 0x7fffffff;
        for (int j = 0; j < 8; ++j) {
            int k = j * 64 + lane;
            const float4* cp = (const float4*)(cg + (long long)k * Dn);
            float d0 = 0.f, d1 = 0.f, d2 = 0.f, d3 = 0.f;
#pragma unroll
            for (int q = 0; q < 16; ++q) {
                float4 v = cp[q];
                d0 = fmaf(v.x, x[4*q+0], d0);
                d1 = fmaf(v.y, x[4*q+1], d1);
                d2 = fmaf(v.z, x[4*q+2], d2);
                d3 = fmaf(v.w, x[4*q+3], d3);
            }
            float dot = (d0 + d1) + (d2 + d3);
            float dist = (xsq + eg[k]) - 2.0f * dot;
            if (dist < best) { best = dist; bk = k; }
        }
#pragma unroll
        for (int m = 1; m < 64; m <<= 1) {
            float ov = __shfl_xor(best, m);
            int   ok = __shfl_xor(bk, m);
            if (ov < best || (ov == best && ok < bk)) { best = ov; bk = ok; }
        }
        if (lane == 0) out[IOFF + (long long)g * Bn + b] = (float)bk;
        out[((long long)g * Bn + b) * Dn + lane] = cg[(long long)bk * Dn + lane];
    }
}

// ---------------------------------------------------------------------------
// per_group_loss = 1.25 * SSE / 2^23; total = sequential sum over 5 groups
// ---------------------------------------------------------------------------
__global__ void vq_finalize(const float* __restrict__ acc, float* __restrict__ out) {
    if (threadIdx.x == 0 && blockIdx.x == 0) {
        float tot = 0.f;
#pragma unroll
        for (int g = 0; g < Gn; ++g) {
            float m = acc[g] / 8388608.0f;
            float l = m + 0.25f * m;
            out[QOFF + g] = l;
            tot += l;
        }
        out[QOFF + Gn] = tot;
    }
}

extern "C" void kernel_launch(void* const* d_in, const int* in_sizes, int n_in,
                              void* d_out, int out_size, void* d_ws, size_t ws_size,
                              hipStream_t stream) {
    const float* feat = (const float*)d_in[0];   // [G,B,D] fp32
    const float* code = (const float*)d_in[1];   // [G,K,D] fp32
    float* out = (float*)d_out;

    char* w = (char*)d_ws;
    float*     acc     = (float*)w;                    // [0,64)
    unsigned*  cnt     = (unsigned*)(w + 64);          // [64,128)
    float*     esq     = (float*)(w + 128);            // 10240 B
    float*     cbias   = (float*)(w + 10368);          // 10240 B
    _Float16*  ch16    = (_Float16*)(w + 20608);       // 327680 B
    _Float16*  cl16    = (_Float16*)(w + 348288);      // 327680 B
    unsigned*  entries = (unsigned*)(w + 675968);      // 49152*4 = 196608 B  (total 872576)

    hipMemsetAsync(w, 0, 128, stream);
    vq_esq<<<(Gn * Kn + 255) / 256, 256, 0, stream>>>(code, esq);
    vq_cvt<<<(Gn * Kn * Dn + 255) / 256, 256, 0, stream>>>(code, esq, ch16, cl16, cbias);
    dim3 grid(Bn / 256, Gn);
    vq_screen<<<grid, 256, 0, stream>>>(feat, code, ch16, cl16, cbias, out, acc, cnt, entries);
    vq_rescue<<<2048, 256, 0, stream>>>(feat, code, esq, cnt, entries, out);
    vq_finalize<<<1, 64, 0, stream>>>(acc, out);
}